// Round 1
// baseline (2537.534 us; speedup 1.0000x reference)
//
#include <hip/hip_runtime.h>

typedef unsigned short u16;
typedef __bf16 bf16x8 __attribute__((ext_vector_type(8)));
typedef float f32x4 __attribute__((ext_vector_type(4)));

#define DEV __device__ __forceinline__

DEV u16 f2b(float f){
  union { float f; unsigned u; } v; v.f = f;
  unsigned r = v.u + 0x7FFFu + ((v.u >> 16) & 1u);
  return (u16)(r >> 16);
}

DEV f32x4 zero4(){ f32x4 z; z[0]=0.f; z[1]=0.f; z[2]=0.f; z[3]=0.f; return z; }

// ---------------- transpose + fp32->bf16: dst[n*K+k] = bf16(src[k*N+n]) -----
template<int K, int N>
__global__ __launch_bounds__(256) void transpose_k(const float* __restrict__ src,
                                                   u16* __restrict__ dst){
  __shared__ float tile[32][33];
  const int z = blockIdx.z;
  const float* s = src + (size_t)z*K*N;
  u16* d = dst + (size_t)z*K*N;
  const int k0 = blockIdx.x*32, n0 = blockIdx.y*32;
  const int tx = threadIdx.x & 31, ty = threadIdx.x >> 5;
  #pragma unroll
  for (int j=0;j<32;j+=8) tile[ty+j][tx] = s[(size_t)(k0+ty+j)*N + n0+tx];
  __syncthreads();
  #pragma unroll
  for (int j=0;j<32;j+=8) d[(size_t)(n0+ty+j)*K + k0+tx] = f2b(tile[tx][ty+j]);
}

// ---------------- embedding: x = traj@W_emb + b_emb + pe[200] ---------------
__global__ __launch_bounds__(256) void embed_kernel(const float* __restrict__ traj,
    const float* __restrict__ We, const float* __restrict__ be,
    const float* __restrict__ pe, float* __restrict__ xf, u16* __restrict__ xb){
  size_t i = (size_t)blockIdx.x*256 + threadIdx.x;   // over 25600*512
  int d = (int)(i & 511); size_t tk = i >> 9;
  float v = traj[tk*2]*We[d] + traj[tk*2+1]*We[512+d] + be[d] + pe[200*512 + d];
  xf[i] = v; xb[i] = f2b(v);
}

// ---------------- GEMM: C[M,N] = A[M,K](bf16) @ Bt[N,K](bf16)^T + bias ------
// 128x128 tile, BK=64, 4 waves 2x2, 4x4 frags of mfma_f32_16x16x32_bf16
template<int K, int N, bool RELU, bool OUT_BF16>
__global__ __launch_bounds__(256) void gemm_bt(const u16* __restrict__ A,
    const u16* __restrict__ Bt, const float* __restrict__ bias,
    void* __restrict__ outp){
  constexpr int LDT = 72;                         // 144B row stride (9*16B)
  __shared__ __align__(16) u16 As[128*LDT];
  __shared__ __align__(16) u16 Bs[128*LDT];
  const int m0 = blockIdx.y*128, n0 = blockIdx.x*128;
  const int t = threadIdx.x, lane = t & 63, w = t >> 6;
  const int wm = (w>>1)*64, wn = (w&1)*64;
  const int g16 = lane>>4, l16 = lane&15;
  f32x4 acc[4][4];
  #pragma unroll
  for (int i=0;i<4;i++)
    #pragma unroll
    for (int j=0;j<4;j++) acc[i][j] = zero4();

  const int lrow = t>>3, lc = (t&7)*8;
  for (int kb=0; kb<K; kb+=64){
    __syncthreads();
    #pragma unroll
    for (int p=0;p<4;p++){
      int r = lrow + 32*p;
      *(uint4*)&As[r*LDT + lc] = *(const uint4*)&A [(size_t)(m0+r)*K + kb + lc];
      *(uint4*)&Bs[r*LDT + lc] = *(const uint4*)&Bt[(size_t)(n0+r)*K + kb + lc];
    }
    __syncthreads();
    #pragma unroll
    for (int ks=0; ks<64; ks+=32){
      const int ko = ks + 8*g16;
      bf16x8 af[4], bfr[4];
      #pragma unroll
      for (int i=0;i<4;i++){
        af[i]  = *(const bf16x8*)&As[(wm + i*16 + l16)*LDT + ko];
        bfr[i] = *(const bf16x8*)&Bs[(wn + i*16 + l16)*LDT + ko];
      }
      #pragma unroll
      for (int mi=0;mi<4;mi++)
        #pragma unroll
        for (int ni=0;ni<4;ni++)
          acc[mi][ni] = __builtin_amdgcn_mfma_f32_16x16x32_bf16(af[mi], bfr[ni], acc[mi][ni], 0,0,0);
    }
  }
  // epilogue
  #pragma unroll
  for (int ni=0; ni<4; ni++){
    const int col = n0 + wn + ni*16 + l16;
    const float bs = bias[col];
    #pragma unroll
    for (int mi=0; mi<4; mi++){
      #pragma unroll
      for (int i=0;i<4;i++){
        const int row = m0 + wm + mi*16 + 4*g16 + i;
        float v = acc[mi][ni][i] + bs;
        if constexpr (RELU) v = fmaxf(v, 0.f);
        if constexpr (OUT_BF16) ((u16*)outp)[(size_t)row*N + col] = f2b(v);
        else                    ((float*)outp)[(size_t)row*N + col] = v;
      }
    }
  }
}

// ---------------- attention: one block per (b,h) ----------------------------
__global__ __launch_bounds__(256) void attn_kernel(const u16* __restrict__ q,
    const u16* __restrict__ k, const u16* __restrict__ v,
    const int* __restrict__ mask, u16* __restrict__ ctx){
  __shared__ __align__(16) u16 Vt[64*232];        // V^T, zero-padded s>=200
  __shared__ __align__(16) u16 Ps[4*16*232];      // per-wave P tiles
  __shared__ float maskadd[208];
  const int bh = blockIdx.x, b = bh>>3, h = bh&7;
  const int t = threadIdx.x, lane = t&63, w = t>>6;
  const int g16 = lane>>4, l16 = lane&15;

  // zero LDS (pads must be exactly 0 so padded K-cols contribute nothing)
  for (int i=t; i<1856; i+=256) ((uint4*)Vt)[i] = make_uint4(0,0,0,0);
  for (int i=t; i<1856; i+=256) ((uint4*)Ps)[i] = make_uint4(0,0,0,0);
  __syncthreads();

  // stage V^T : Vt[d][s] = V[s][d]
  #pragma unroll
  for (int ii=0; ii<16; ii++){
    int d = w + 4*ii;
    for (int s = lane; s < 200; s += 64)
      Vt[d*232 + s] = v[((size_t)(b*200+s))*512 + h*64 + d];
  }
  if (t < 208) maskadd[t] = (t < 200 && mask[b*200+t] != 0) ? 0.f : -1e30f;
  __syncthreads();

  u16* Pw = Ps + w*16*232;
  const float scale = 0.125f;   // 1/sqrt(64)

  for (int rt = w; rt < 13; rt += 4){
    const int rbase = rt*16;
    f32x4 sc[13];
    #pragma unroll
    for (int ct=0;ct<13;ct++) sc[ct] = zero4();

    // scores = Q K^T  (A-frag rows of Q, B-frag rows of K, both contiguous)
    #pragma unroll
    for (int ks=0; ks<64; ks+=32){
      const int ko = ks + 8*g16;
      const size_t qrow = (size_t)(b*200) + rbase + l16;
      bf16x8 aq = *(const bf16x8*)&q[qrow*512 + h*64 + ko];
      #pragma unroll
      for (int ct=0; ct<13; ct++){
        const size_t krow = (size_t)(b*200) + ct*16 + l16;
        bf16x8 bk8 = *(const bf16x8*)&k[krow*512 + h*64 + ko];
        sc[ct] = __builtin_amdgcn_mfma_f32_16x16x32_bf16(aq, bk8, sc[ct], 0,0,0);
      }
    }

    // scale + mask + row softmax (rows live in 16-lane groups)
    float mx[4] = {-1e30f,-1e30f,-1e30f,-1e30f};
    #pragma unroll
    for (int ct=0;ct<13;ct++){
      float ma = maskadd[ct*16 + l16];
      #pragma unroll
      for (int i=0;i<4;i++){
        float s0 = sc[ct][i]*scale + ma;
        sc[ct][i] = s0;
        mx[i] = fmaxf(mx[i], s0);
      }
    }
    #pragma unroll
    for (int i=0;i<4;i++)
      for (int d=1; d<16; d<<=1) mx[i] = fmaxf(mx[i], __shfl_xor(mx[i], d));
    float sm[4] = {0.f,0.f,0.f,0.f};
    #pragma unroll
    for (int ct=0;ct<13;ct++)
      #pragma unroll
      for (int i=0;i<4;i++){
        float e = __expf(sc[ct][i] - mx[i]);
        sc[ct][i] = e; sm[i] += e;
      }
    #pragma unroll
    for (int i=0;i<4;i++)
      for (int d=1; d<16; d<<=1) sm[i] += __shfl_xor(sm[i], d);
    float rs[4];
    #pragma unroll
    for (int i=0;i<4;i++) rs[i] = 1.f/sm[i];

    // P -> LDS (bf16)
    #pragma unroll
    for (int ct=0;ct<13;ct++)
      #pragma unroll
      for (int i=0;i<4;i++)
        Pw[(4*g16+i)*232 + ct*16 + l16] = f2b(sc[ct][i]);
    asm volatile("s_waitcnt lgkmcnt(0)" ::: "memory");

    // ctx = P @ V   (A-frag rows of P, B-frag rows of V^T)
    f32x4 cacc[4];
    #pragma unroll
    for (int ni=0;ni<4;ni++) cacc[ni] = zero4();
    #pragma unroll
    for (int kt=0; kt<7; kt++){
      const int ko = kt*32 + 8*g16;
      bf16x8 ap = *(const bf16x8*)&Pw[l16*232 + ko];
      #pragma unroll
      for (int ni=0; ni<4; ni++){
        bf16x8 bv8 = *(const bf16x8*)&Vt[(ni*16 + l16)*232 + ko];
        cacc[ni] = __builtin_amdgcn_mfma_f32_16x16x32_bf16(ap, bv8, cacc[ni], 0,0,0);
      }
    }
    #pragma unroll
    for (int ni=0;ni<4;ni++)
      #pragma unroll
      for (int i=0;i<4;i++){
        const int r = rbase + 4*g16 + i;
        if (r < 200)
          ctx[((size_t)(b*200+r))*512 + h*64 + ni*16 + l16] = f2b(cacc[ni][i]*rs[i]);
      }
  }
}

// ---------------- residual + LayerNorm (one wave per 512-row) ---------------
template<bool RESID, bool WRITE_BF>
__global__ __launch_bounds__(256) void add_ln_kernel(const float* __restrict__ xin,
    const float* __restrict__ yin, const float* __restrict__ gam,
    const float* __restrict__ bet, float* __restrict__ fout,
    u16* __restrict__ bfout){
  const int r = blockIdx.x*4 + (threadIdx.x>>6);
  const int lane = threadIdx.x & 63;
  const size_t base = (size_t)r*512 + lane*8;
  float4 a0 = *(const float4*)&xin[base];
  float4 a1 = *(const float4*)&xin[base+4];
  if constexpr (RESID){
    float4 y0 = *(const float4*)&yin[base];
    float4 y1 = *(const float4*)&yin[base+4];
    a0.x+=y0.x; a0.y+=y0.y; a0.z+=y0.z; a0.w+=y0.w;
    a1.x+=y1.x; a1.y+=y1.y; a1.z+=y1.z; a1.w+=y1.w;
  }
  float vv[8] = {a0.x,a0.y,a0.z,a0.w,a1.x,a1.y,a1.z,a1.w};
  float s=0.f, q2=0.f;
  #pragma unroll
  for (int j=0;j<8;j++){ s += vv[j]; q2 += vv[j]*vv[j]; }
  #pragma unroll
  for (int d=1; d<64; d<<=1){ s += __shfl_xor(s,d); q2 += __shfl_xor(q2,d); }
  const float mean = s * (1.f/512.f);
  const float var  = q2 * (1.f/512.f) - mean*mean;
  const float rstd = rsqrtf(var + 1e-5f);
  const int col = lane*8;
  float4 g0 = *(const float4*)&gam[col], g1 = *(const float4*)&gam[col+4];
  float4 b0 = *(const float4*)&bet[col], b1 = *(const float4*)&bet[col+4];
  float gg[8] = {g0.x,g0.y,g0.z,g0.w,g1.x,g1.y,g1.z,g1.w};
  float bb[8] = {b0.x,b0.y,b0.z,b0.w,b1.x,b1.y,b1.z,b1.w};
  float o[8];
  #pragma unroll
  for (int j=0;j<8;j++) o[j] = (vv[j]-mean)*rstd*gg[j] + bb[j];
  float4 w0 = {o[0],o[1],o[2],o[3]}, w1 = {o[4],o[5],o[6],o[7]};
  *(float4*)&fout[base] = w0;
  *(float4*)&fout[base+4] = w1;
  if constexpr (WRITE_BF){
    union { u16 pk[8]; uint4 v; } u;
    #pragma unroll
    for (int j=0;j<8;j++) u.pk[j] = f2b(o[j]);
    *(uint4*)&bfout[base] = u.v;
  }
}

// ---------------------------------------------------------------------------
extern "C" void kernel_launch(void* const* d_in, const int* in_sizes, int n_in,
                              void* d_out, int out_size, void* d_ws, size_t ws_size,
                              hipStream_t stream){
  const float* traj = (const float*)d_in[0];
  const int*   mask = (const int*)  d_in[1];
  const float* pe   = (const float*)d_in[2];
  const float* We   = (const float*)d_in[3];
  const float* be   = (const float*)d_in[4];
  const float* Wq   = (const float*)d_in[5];
  const float* bq   = (const float*)d_in[6];
  const float* Wk   = (const float*)d_in[7];
  const float* bk   = (const float*)d_in[8];
  const float* Wv   = (const float*)d_in[9];
  const float* bv   = (const float*)d_in[10];
  const float* Wo   = (const float*)d_in[11];
  const float* bo   = (const float*)d_in[12];
  const float* ln1g = (const float*)d_in[13];
  const float* ln1b = (const float*)d_in[14];
  const float* W1   = (const float*)d_in[15];
  const float* b1   = (const float*)d_in[16];
  const float* W2   = (const float*)d_in[17];
  const float* b2   = (const float*)d_in[18];
  const float* ln2g = (const float*)d_in[19];
  const float* ln2b = (const float*)d_in[20];
  const float* lnfg = (const float*)d_in[21];
  const float* lnfb = (const float*)d_in[22];

  const size_t PROJ = 512*512, FFW = 512*2048, TOK = (size_t)25600*512;
  u16* Wqt = (u16*)d_ws;
  u16* Wkt = Wqt + 6*PROJ;
  u16* Wvt = Wkt + 6*PROJ;
  u16* Wot = Wvt + 6*PROJ;
  u16* W1t = Wot + 6*PROJ;       // [2048][512] per layer
  u16* W2t = W1t + 6*FFW;        // [512][2048] per layer
  float* xf = (float*)(W2t + 6*FFW);
  u16* xb  = (u16*)(xf + TOK);
  u16* qb  = xb + TOK;
  u16* kb2 = qb + TOK;
  u16* vb2 = kb2 + TOK;
  u16* cb  = vb2 + TOK;
  u16* ffb = qb;                 // aliases q/k/v/ctx (dead during FF phase)
  float* gout = (float*)d_out;   // f32 GEMM scratch; rewritten by final LN

  dim3 B256(256);
  transpose_k<512,512> <<<dim3(16,16,6), B256, 0, stream>>>(Wq, Wqt);
  transpose_k<512,512> <<<dim3(16,16,6), B256, 0, stream>>>(Wk, Wkt);
  transpose_k<512,512> <<<dim3(16,16,6), B256, 0, stream>>>(Wv, Wvt);
  transpose_k<512,512> <<<dim3(16,16,6), B256, 0, stream>>>(Wo, Wot);
  transpose_k<512,2048><<<dim3(16,64,6), B256, 0, stream>>>(W1, W1t);
  transpose_k<2048,512><<<dim3(64,16,6), B256, 0, stream>>>(W2, W2t);

  embed_kernel<<<51200, B256, 0, stream>>>(traj, We, be, pe, xf, xb);

  for (int i=0; i<6; i++){
    gemm_bt<512,512,false,true> <<<dim3(4,200), B256, 0, stream>>>(xb, Wqt + (size_t)i*PROJ, bq + i*512, qb);
    gemm_bt<512,512,false,true> <<<dim3(4,200), B256, 0, stream>>>(xb, Wkt + (size_t)i*PROJ, bk + i*512, kb2);
    gemm_bt<512,512,false,true> <<<dim3(4,200), B256, 0, stream>>>(xb, Wvt + (size_t)i*PROJ, bv + i*512, vb2);
    attn_kernel<<<1024, B256, 0, stream>>>(qb, kb2, vb2, mask, cb);
    gemm_bt<512,512,false,false><<<dim3(4,200), B256, 0, stream>>>(cb, Wot + (size_t)i*PROJ, bo + i*512, gout);
    add_ln_kernel<true,true><<<6400, B256, 0, stream>>>(xf, gout, ln1g + i*512, ln1b + i*512, xf, xb);
    gemm_bt<512,2048,true,true> <<<dim3(16,200), B256, 0, stream>>>(xb, W1t + (size_t)i*FFW, b1 + i*2048, ffb);
    gemm_bt<2048,512,false,false><<<dim3(4,200), B256, 0, stream>>>(ffb, W2t + (size_t)i*FFW, b2 + i*512, gout);
    add_ln_kernel<true,true><<<6400, B256, 0, stream>>>(xf, gout, ln2g + i*512, ln2b + i*512, xf, xb);
  }
  add_ln_kernel<false,false><<<6400, B256, 0, stream>>>(xf, xf, lnfg, lnfb, gout, nullptr);
}